// Round 4
// baseline (449.643 us; speedup 1.0000x reference)
//
#include <hip/hip_runtime.h>
#include <math.h>

#define B_    32
#define C_IN  12
#define C_HID 16
#define H_    495
#define W_    436
#define HW    (H_ * W_)        // 215820 (divisible by 4)
#define NPIX  (B_ * HW)        // 6906240
#define NG4   (NPIX / 4)       // 1726560 threads, 4 px each

typedef float v2f __attribute__((ext_vector_type(2)));

static __device__ __forceinline__ v2f pk_fma(v2f a, float w, v2f c) {
#if __has_builtin(__builtin_elementwise_fma)
    v2f ws = {w, w};
    return __builtin_elementwise_fma(a, ws, c);
#else
    v2f r; r.x = fmaf(a.x, w, c.x); r.y = fmaf(a.y, w, c.y); return r;
#endif
}

static __device__ __forceinline__ v2f pk_relu(v2f a) {
#if __has_builtin(__builtin_elementwise_max)
    v2f z = {0.0f, 0.0f};
    return __builtin_elementwise_max(a, z);
#else
    v2f r; r.x = fmaxf(a.x, 0.0f); r.y = fmaxf(a.y, 0.0f); return r;
#endif
}

// One thread = 4 consecutive W-pixels as two packed float2 lanes.
// Each LDS weight-row read (1 KB/wave broadcast cost) now feeds 4 pixels
// instead of 2 -> LDS return-path ~497 B/px < HBM 52 B/px * (128/10.25),
// i.e. HBM-bound. Layer-3 folded into layer-2 loop to kill the h2 array.
__global__ __launch_bounds__(256) void temporal_mlp_kernel(
    const float* __restrict__ x,
    const float* __restrict__ w1, const float* __restrict__ b1,
    const float* __restrict__ w2, const float* __restrict__ b2,
    const float* __restrict__ w3, const float* __restrict__ b3,
    float* __restrict__ out)
{
    __shared__ __align__(16) float4 sW1[16][3];  // w1 * (1/255): folds x/255
    __shared__ __align__(16) float4 sW2[16][4];
    __shared__ float sW3f[16];
    __shared__ float sB1[16];                    // b1 - 0.5*rowsum(w1): folds -0.5
    __shared__ float sB2[16];
    __shared__ float sB3;

    const int tid = threadIdx.x;
    {
        float* pW1 = (float*)sW1;
        float* pW2 = (float*)sW2;
        if (tid < 192) pW1[tid] = w1[tid] * (1.0f / 255.0f);
        pW2[tid] = w2[tid];                      // exactly 256 elements
        if (tid < 16) {
            float s = 0.0f;
            #pragma unroll
            for (int c = 0; c < 12; ++c) s += w1[tid * 12 + c];
            sB1[tid] = b1[tid] - 0.5f * s;
            sB2[tid] = b2[tid];
            sW3f[tid] = w3[tid];
        }
        if (tid == 0) sB3 = b3[0];
    }
    __syncthreads();

    const int g = blockIdx.x * 256 + tid;
    if (g >= NG4) return;

    const int base = g * 4;                  // flat pixel index over [B, H*W]
    const int b    = base / HW;              // compile-time magic-mul
    const int p    = base - b * HW;          // multiple of 4 -> float4 aligned
    const float* xb = x + (size_t)b * (C_IN * HW) + p;

    // 12 coalesced float4 loads (one per input-channel plane), 16 B/lane.
    v2f xn0[12], xn1[12];
    #pragma unroll
    for (int c = 0; c < 12; ++c) {
        float4 t = *(const float4*)(xb + (size_t)c * HW);
        v2f u = {t.x, t.y};
        v2f v = {t.z, t.w};
        xn0[c] = u;
        xn1[c] = v;
    }

    // ---- layer 1: 12 -> 16, relu (x/255 - 0.5 folded into sW1/sB1) ----
    v2f h10[16], h11[16];
    #pragma unroll
    for (int o = 0; o < 16; ++o) {
        const float4 wa = sW1[o][0];
        const float4 wb = sW1[o][1];
        const float4 wc = sW1[o][2];
        const float bb = sB1[o];
        v2f a0 = {bb, bb}, a1 = {bb, bb};
        a0 = pk_fma(xn0[0],  wa.x, a0);  a1 = pk_fma(xn1[0],  wa.x, a1);
        a0 = pk_fma(xn0[1],  wa.y, a0);  a1 = pk_fma(xn1[1],  wa.y, a1);
        a0 = pk_fma(xn0[2],  wa.z, a0);  a1 = pk_fma(xn1[2],  wa.z, a1);
        a0 = pk_fma(xn0[3],  wa.w, a0);  a1 = pk_fma(xn1[3],  wa.w, a1);
        a0 = pk_fma(xn0[4],  wb.x, a0);  a1 = pk_fma(xn1[4],  wb.x, a1);
        a0 = pk_fma(xn0[5],  wb.y, a0);  a1 = pk_fma(xn1[5],  wb.y, a1);
        a0 = pk_fma(xn0[6],  wb.z, a0);  a1 = pk_fma(xn1[6],  wb.z, a1);
        a0 = pk_fma(xn0[7],  wb.w, a0);  a1 = pk_fma(xn1[7],  wb.w, a1);
        a0 = pk_fma(xn0[8],  wc.x, a0);  a1 = pk_fma(xn1[8],  wc.x, a1);
        a0 = pk_fma(xn0[9],  wc.y, a0);  a1 = pk_fma(xn1[9],  wc.y, a1);
        a0 = pk_fma(xn0[10], wc.z, a0);  a1 = pk_fma(xn1[10], wc.z, a1);
        a0 = pk_fma(xn0[11], wc.w, a0);  a1 = pk_fma(xn1[11], wc.w, a1);
        h10[o] = pk_relu(a0);
        h11[o] = pk_relu(a1);
    }

    // ---- layer 2 (16 -> 16, relu) fused with layer 3 (16 -> 1) ----
    const float b3v = sB3;
    v2f t0 = {b3v, b3v}, t1 = {b3v, b3v};
    #pragma unroll
    for (int o = 0; o < 16; ++o) {
        const float4 wa = sW2[o][0];
        const float4 wb = sW2[o][1];
        const float4 wc = sW2[o][2];
        const float4 wd = sW2[o][3];
        const float bb = sB2[o];
        v2f a0 = {bb, bb}, a1 = {bb, bb};
        a0 = pk_fma(h10[0],  wa.x, a0);  a1 = pk_fma(h11[0],  wa.x, a1);
        a0 = pk_fma(h10[1],  wa.y, a0);  a1 = pk_fma(h11[1],  wa.y, a1);
        a0 = pk_fma(h10[2],  wa.z, a0);  a1 = pk_fma(h11[2],  wa.z, a1);
        a0 = pk_fma(h10[3],  wa.w, a0);  a1 = pk_fma(h11[3],  wa.w, a1);
        a0 = pk_fma(h10[4],  wb.x, a0);  a1 = pk_fma(h11[4],  wb.x, a1);
        a0 = pk_fma(h10[5],  wb.y, a0);  a1 = pk_fma(h11[5],  wb.y, a1);
        a0 = pk_fma(h10[6],  wb.z, a0);  a1 = pk_fma(h11[6],  wb.z, a1);
        a0 = pk_fma(h10[7],  wb.w, a0);  a1 = pk_fma(h11[7],  wb.w, a1);
        a0 = pk_fma(h10[8],  wc.x, a0);  a1 = pk_fma(h11[8],  wc.x, a1);
        a0 = pk_fma(h10[9],  wc.y, a0);  a1 = pk_fma(h11[9],  wc.y, a1);
        a0 = pk_fma(h10[10], wc.z, a0);  a1 = pk_fma(h11[10], wc.z, a1);
        a0 = pk_fma(h10[11], wc.w, a0);  a1 = pk_fma(h11[11], wc.w, a1);
        a0 = pk_fma(h10[12], wd.x, a0);  a1 = pk_fma(h11[12], wd.x, a1);
        a0 = pk_fma(h10[13], wd.y, a0);  a1 = pk_fma(h11[13], wd.y, a1);
        a0 = pk_fma(h10[14], wd.z, a0);  a1 = pk_fma(h11[14], wd.z, a1);
        a0 = pk_fma(h10[15], wd.w, a0);  a1 = pk_fma(h11[15], wd.w, a1);
        const float w3o = sW3f[o];
        t0 = pk_fma(pk_relu(a0), w3o, t0);
        t1 = pk_fma(pk_relu(a1), w3o, t1);
    }

    float4 r;
    r.x = 255.0f / (1.0f + __expf(-t0.x));
    r.y = 255.0f / (1.0f + __expf(-t0.y));
    r.z = 255.0f / (1.0f + __expf(-t1.x));
    r.w = 255.0f / (1.0f + __expf(-t1.y));
    *(float4*)(out + base) = r;
}

extern "C" void kernel_launch(void* const* d_in, const int* in_sizes, int n_in,
                              void* d_out, int out_size, void* d_ws, size_t ws_size,
                              hipStream_t stream) {
    const float* x  = (const float*)d_in[0];
    const float* w1 = (const float*)d_in[1];
    const float* b1 = (const float*)d_in[2];
    const float* w2 = (const float*)d_in[3];
    const float* b2 = (const float*)d_in[4];
    const float* w3 = (const float*)d_in[5];
    const float* b3 = (const float*)d_in[6];
    float* out = (float*)d_out;

    const int grid = (NG4 + 255) / 256;  // 6745 blocks of 256
    temporal_mlp_kernel<<<grid, 256, 0, stream>>>(x, w1, b1, w2, b2, w3, b3, out);
}